// Round 18
// baseline (453.995 us; speedup 1.0000x reference)
//
#include <hip/hip_runtime.h>
#include <hip/hip_bf16.h>
#include <math.h>

#define N_NODES 100000
#define N_EDGES 1600000
#define IN_FEATS 256
#define OUT_FEATS 64
#define NHEAD 4
#define F_TOT 256
#define ALPHA 0.2f

typedef __attribute__((ext_vector_type(8))) short short8;
typedef __attribute__((ext_vector_type(8))) unsigned short ush8;
typedef __attribute__((ext_vector_type(4))) float f32x4;

// ---------------- workspace layout (bytes) ----------------
#define OFF_HB    ((size_t)0)            // 51,200,000
#define OFF_HL    ((size_t)51200000)     // 1,600,000
#define OFF_HR    ((size_t)52800000)     // 1,600,000
#define OFF_CNT   ((size_t)54400000)     // 400,128
#define OFF_OFFS  ((size_t)54800128)     // 400,128
#define OFF_CUR   ((size_t)55200256)     // 400,128
#define OFF_CSORT ((size_t)55600384)     // 6,400,000
#define OFF_ESORT ((size_t)62000384)     // E * 8 = 12,800,000 (bf16 x4)
#define OFF_BSUM  ((size_t)74800384)     // 4,096
#define OFF_WP    ((size_t)74804480)     // 131,072 (fragment-packed W)

__device__ inline float bf2f(ushort u) { return __uint_as_float((uint)u << 16); }
__device__ inline ushort f2bf(float f) {
  __hip_bfloat16 b = __float2bfloat16(f);
  return *(ushort*)&b;
}

// ---------------- prep: W fragment-pack (blocks 0-15) + hist (blocks 16+) ----------------
#define PREP_CAST_BLKS 16
#define PREP_HIST_BLKS 512

__global__ __launch_bounds__(256) void prep_kernel(const float* __restrict__ W,
                                                   ushort* __restrict__ Wp,
                                                   const int* __restrict__ row,
                                                   int* __restrict__ counts, int E) {
  if (blockIdx.x < PREP_CAST_BLKS) {
    #pragma unroll
    for (int it = 0; it < 2; ++it) {
      const int f = blockIdx.x * 512 + it * 256 + threadIdx.x;
      const int lane = f & 63;
      const int j = (f >> 6) & 3;
      const int k = (f >> 8) & 7;
      const int h = f >> 11;
      const int lr = lane & 15;
      const int kq = lane >> 4;
      const int colW = h * 64 + j * 16 + lr;
      union { ushort u[8]; short8 s; } t;
      #pragma unroll
      for (int e = 0; e < 8; ++e)
        t.u[e] = f2bf(W[(size_t)(k * 32 + kq * 8 + e) * F_TOT + colW]);
      *(short8*)&Wp[(size_t)f * 8] = t.s;
    }
  } else {
    int gtid = (blockIdx.x - PREP_CAST_BLKS) * 256 + threadIdx.x;
    for (int i = gtid; i < E; i += PREP_HIST_BLKS * 256)
      atomicAdd(&counts[row[i]], 1);
  }
}

// ---------------- MFMA GEMM: 1 wave/block, 16 rows x 256 cols, no barriers ----------------
// A-frags global->reg (each X row read once chip-wide); B from L2-hot packed Wp.
#define NRB16 6250   // ceil(100000/16)

__global__ __launch_bounds__(64) void gemm_bf16(const float* __restrict__ X,
                                                const ushort* __restrict__ Wp,
                                                ushort* __restrict__ hb,
                                                const float* __restrict__ a_l,
                                                const float* __restrict__ a_r,
                                                float* __restrict__ hl,
                                                float* __restrict__ hr, int M) {
  __shared__ __align__(16) ushort Hs[16][F_TOT + 8];   // 8,448 B, wave-private
  const int row0 = blockIdx.x * 16;
  const int lane = threadIdx.x;
  const int lr = lane & 15;
  const int kq = lane >> 4;        // 0..3

  // A fragments: 8 frags cover K=256 for rows row0..row0+15
  const int myrow = row0 + lr;
  short8 af[8];
  #pragma unroll
  for (int k = 0; k < 8; ++k) {
    union { ushort u[8]; short8 s; } t;
    if (myrow < M) {
      const float* src = &X[(size_t)myrow * IN_FEATS + k * 32 + kq * 8];
      const float4 f0 = *(const float4*)(src);
      const float4 f1 = *(const float4*)(src + 4);
      t.u[0] = f2bf(f0.x); t.u[1] = f2bf(f0.y); t.u[2] = f2bf(f0.z); t.u[3] = f2bf(f0.w);
      t.u[4] = f2bf(f1.x); t.u[5] = f2bf(f1.y); t.u[6] = f2bf(f1.z); t.u[7] = f2bf(f1.w);
    } else {
      t.s = (short8)(0);
    }
    af[k] = t.s;
  }

  f32x4 acc[16];
  #pragma unroll
  for (int j = 0; j < 16; ++j) acc[j] = (f32x4)(0.f);

  // MFMA: 16 col-frags (j16) x 8 k
  const ushort* wpL = &Wp[(size_t)lane * 8];
  #pragma unroll
  for (int k = 0; k < 8; ++k) {
    #pragma unroll
    for (int j16 = 0; j16 < 16; ++j16) {
      const int h = j16 >> 2, j = j16 & 3;
      const short8 bf = *(const short8*)&wpL[(size_t)(((h * 8 + k) * 4 + j) * 64) * 8];
      acc[j16] = __builtin_amdgcn_mfma_f32_16x16x32_bf16(af[k], bf, acc[j16], 0, 0, 0);
    }
  }

  // epilogue A: hl/hr (4 heads, rows kq*4+reg)
  #pragma unroll
  for (int h = 0; h < 4; ++h) {
    const float alv0 = a_l[h * OUT_FEATS + 0 * 16 + lr];
    const float alv1 = a_l[h * OUT_FEATS + 1 * 16 + lr];
    const float alv2 = a_l[h * OUT_FEATS + 2 * 16 + lr];
    const float alv3 = a_l[h * OUT_FEATS + 3 * 16 + lr];
    const float arv0 = a_r[h * OUT_FEATS + 0 * 16 + lr];
    const float arv1 = a_r[h * OUT_FEATS + 1 * 16 + lr];
    const float arv2 = a_r[h * OUT_FEATS + 2 * 16 + lr];
    const float arv3 = a_r[h * OUT_FEATS + 3 * 16 + lr];
    #pragma unroll
    for (int reg = 0; reg < 4; ++reg) {
      float pl = acc[h * 4 + 0][reg] * alv0 + acc[h * 4 + 1][reg] * alv1
               + acc[h * 4 + 2][reg] * alv2 + acc[h * 4 + 3][reg] * alv3;
      float pr = acc[h * 4 + 0][reg] * arv0 + acc[h * 4 + 1][reg] * arv1
               + acc[h * 4 + 2][reg] * arv2 + acc[h * 4 + 3][reg] * arv3;
      #pragma unroll
      for (int d = 8; d >= 1; d >>= 1) {
        pl += __shfl_xor(pl, d);
        pr += __shfl_xor(pr, d);
      }
      if (lr == 0) {
        const int r = row0 + kq * 4 + reg;
        if (r < M) {
          hl[r * NHEAD + h] = pl;
          hr[r * NHEAD + h] = pr;
        }
      }
    }
  }

  // epilogue B: transpose through LDS -> coalesced 16B stores
  #pragma unroll
  for (int j16 = 0; j16 < 16; ++j16) {
    #pragma unroll
    for (int reg = 0; reg < 4; ++reg)
      Hs[kq * 4 + reg][j16 * 16 + lr] = f2bf(acc[j16][reg]);
  }
  __syncthreads();   // single-wave block: compiles to waitcnt only
  #pragma unroll
  for (int it = 0; it < 8; ++it) {
    const int idx = it * 64 + lane;
    const int r = idx >> 5;
    const int c8 = (idx & 31) * 8;
    const int gr = row0 + r;
    if (gr < M)
      *(ush8*)&hb[(size_t)gr * F_TOT + c8] = *(const ush8*)&Hs[r][c8];
  }
}

// ---------------- CSR scan (plain launches) ----------------
__global__ __launch_bounds__(1024) void scan1_kernel(const int* __restrict__ counts,
                                                     int* __restrict__ offsets,
                                                     int* __restrict__ bsum, int n) {
  __shared__ int wsum[16];
  const int tid = threadIdx.x;
  const int lane = tid & 63;
  const int wid = tid >> 6;
  int i = blockIdx.x * 1024 + tid;
  int v = (i < n) ? counts[i] : 0;
  int inc = v;
  #pragma unroll
  for (int d = 1; d < 64; d <<= 1) {
    int t = __shfl_up(inc, d);
    if (lane >= d) inc += t;
  }
  if (lane == 63) wsum[wid] = inc;
  __syncthreads();
  if (tid < 16) {
    int x = wsum[tid];
    #pragma unroll
    for (int d = 1; d < 16; d <<= 1) {
      int t = __shfl_up(x, d);
      if (tid >= d) x += t;
    }
    wsum[tid] = x;
  }
  __syncthreads();
  int excl = ((wid > 0) ? wsum[wid - 1] : 0) + inc - v;
  if (i < n) offsets[i] = excl;
  if (tid == 0) bsum[blockIdx.x] = wsum[15];
}

// scan3 with scan2 folded in
__global__ __launch_bounds__(256) void scan3_kernel(int* __restrict__ offsets,
                                                    int* __restrict__ cursor,
                                                    const int* __restrict__ bsum,
                                                    int n, int nblk) {
  __shared__ int sb[132];
  const int tid = threadIdx.x;
  if (tid < 64) {
    int run = 0;
    for (int base = 0; base < nblk; base += 64) {
      int idx = base + tid;
      int v = (idx < nblk) ? bsum[idx] : 0;
      int inc = v;
      #pragma unroll
      for (int d = 1; d < 64; d <<= 1) {
        int t = __shfl_up(inc, d);
        if (tid >= d) inc += t;
      }
      if (idx < nblk) sb[idx] = run + inc - v;
      run += __shfl(inc, 63);
    }
    if (tid == 0) sb[nblk] = run;
  }
  __syncthreads();
  int i = blockIdx.x * blockDim.x + tid;
  if (i < n) {
    int off = offsets[i] + sb[i >> 10];
    offsets[i] = off;
    cursor[i] = off;
  }
  if (i == 0) offsets[n] = sb[nblk];
}

// ---------------- scatter + per-edge exp weights (bf16 x4 = 8B) ----------------
__global__ void scatter_esort(const int* __restrict__ row, const int* __restrict__ col,
                              const float* __restrict__ hl, const float* __restrict__ hr,
                              int* __restrict__ cursor, int* __restrict__ col_sorted,
                              ushort* __restrict__ esort, int E) {
  int i = blockIdx.x * blockDim.x + threadIdx.x;
  if (i >= E) return;
  const int r = row[i];
  const int c = col[i];
  const float4 l4 = *(const float4*)&hl[r * NHEAD];
  const float4 r4 = *(const float4*)&hr[c * NHEAD];
  float e0 = l4.x + r4.x, e1 = l4.y + r4.y, e2 = l4.z + r4.z, e3 = l4.w + r4.w;
  e0 = e0 > 0.f ? e0 : ALPHA * e0;
  e1 = e1 > 0.f ? e1 : ALPHA * e1;
  e2 = e2 > 0.f ? e2 : ALPHA * e2;
  e3 = e3 > 0.f ? e3 : ALPHA * e3;
  union { ushort u[4]; ushort4 v; } w;
  w.u[0] = f2bf(__expf(e0));
  w.u[1] = f2bf(__expf(e1));
  w.u[2] = f2bf(__expf(e2));
  w.u[3] = f2bf(__expf(e3));
  int p = atomicAdd(&cursor[r], 1);
  col_sorted[p] = c;
  *(ushort4*)&esort[(size_t)p * 4] = w.v;
}

// ---------------- aggregation (R15-proven): wave/node, two streams, 4-wide MLP ----------------
__global__ __launch_bounds__(256) void agg_kernel(const ushort* __restrict__ hb,
                                                  const int* __restrict__ col_sorted,
                                                  const ushort* __restrict__ esort,
                                                  const int* __restrict__ offsets,
                                                  float* __restrict__ out, int n) {
  int node = blockIdx.x * 4 + (threadIdx.x >> 6);
  int lane = threadIdx.x & 63;
  if (node >= n) return;
  const int s = offsets[node];
  const int t = offsets[node + 1];
  const int half = lane >> 5;
  const int fl = lane & 31;
  const int head = fl >> 3;

  float denom = 0.f;
  float a[8] = {0.f, 0.f, 0.f, 0.f, 0.f, 0.f, 0.f, 0.f};
  const size_t fo = (size_t)fl * 8;

  auto edge = [&](int ii) {
    const int c = col_sorted[ii];
    const float w = bf2f(esort[(size_t)ii * 4 + head]);
    union { ush8 v; ushort u[8]; } hv;
    hv.v = *(const ush8*)&hb[(size_t)c * F_TOT + fo];
    denom += w;
    #pragma unroll
    for (int j = 0; j < 8; ++j) a[j] = fmaf(w, bf2f(hv.u[j]), a[j]);
  };

  int i = s + half;
  for (; i + 6 < t; i += 8) { edge(i); edge(i + 2); edge(i + 4); edge(i + 6); }
  for (; i < t; i += 2) edge(i);

  denom += __shfl_xor(denom, 32);
  #pragma unroll
  for (int j = 0; j < 8; ++j) a[j] += __shfl_xor(a[j], 32);

  const float inv = 1.f / (denom + 1e-16f);
  float4 o = make_float4(a[half * 4 + 0] * inv, a[half * 4 + 1] * inv,
                         a[half * 4 + 2] * inv, a[half * 4 + 3] * inv);
  *(float4*)&out[(size_t)node * F_TOT + fl * 8 + half * 4] = o;
}

// ---------------- launcher ----------------
extern "C" void kernel_launch(void* const* d_in, const int* in_sizes, int n_in,
                              void* d_out, int out_size, void* d_ws, size_t ws_size,
                              hipStream_t stream) {
  const float* x   = (const float*)d_in[0];
  const float* W   = (const float*)d_in[1];
  const float* a_l = (const float*)d_in[2];
  const float* a_r = (const float*)d_in[3];
  const int*   row = (const int*)d_in[4];
  const int*   col = (const int*)d_in[5];
  float* out = (float*)d_out;

  int n = in_sizes[0] / IN_FEATS;   // 100000
  int E = in_sizes[4];              // 1600000

  char* ws = (char*)d_ws;
  ushort* hb      = (ushort*)(ws + OFF_HB);
  float*  hl      = (float*)(ws + OFF_HL);
  float*  hr      = (float*)(ws + OFF_HR);
  int* counts     = (int*)(ws + OFF_CNT);
  int* offsets    = (int*)(ws + OFF_OFFS);
  int* cursor     = (int*)(ws + OFF_CUR);
  int* col_sorted = (int*)(ws + OFF_CSORT);
  ushort* esort   = (ushort*)(ws + OFF_ESORT);
  int* bsum       = (int*)(ws + OFF_BSUM);
  ushort* Wp      = (ushort*)(ws + OFF_WP);

  // 1. zero counts
  hipMemsetAsync(counts, 0, (size_t)(n + 1) * sizeof(int), stream);
  // 2. prep: W fragment-pack + histogram
  prep_kernel<<<PREP_CAST_BLKS + PREP_HIST_BLKS, 256, 0, stream>>>(W, Wp, row, counts, E);
  // 3. GEMM (1 wave/block, no barriers, X read once, L2-hot packed B)
  gemm_bf16<<<NRB16, 64, 0, stream>>>(x, Wp, hb, a_l, a_r, hl, hr, n);
  // 4. CSR scan (plain launches)
  int nblk = (n + 1023) / 1024;  // 98
  scan1_kernel<<<nblk, 1024, 0, stream>>>(counts, offsets, bsum, n);
  scan3_kernel<<<(n + 255) / 256, 256, 0, stream>>>(offsets, cursor, bsum, n, nblk);
  // 5. scatter (col 4B + bf16 weights 8B)
  scatter_esort<<<(E + 255) / 256, 256, 0, stream>>>(row, col, hl, hr, cursor,
                                                     col_sorted, esort, E);
  // 6. aggregation
  agg_kernel<<<(n + 3) / 4, 256, 0, stream>>>(hb, col_sorted, esort, offsets, out, n);
}

// Round 20
// 345.625 us; speedup vs baseline: 1.3135x; 1.3135x over previous
//
#include <hip/hip_runtime.h>
#include <hip/hip_bf16.h>
#include <math.h>

#define N_NODES 100000
#define N_EDGES 1600000
#define IN_FEATS 256
#define OUT_FEATS 64
#define NHEAD 4
#define F_TOT 256
#define ALPHA 0.2f

typedef __attribute__((ext_vector_type(8))) short short8;
typedef __attribute__((ext_vector_type(8))) unsigned short ush8;
typedef __attribute__((ext_vector_type(4))) float f32x4;

// ---------------- workspace layout (bytes) ----------------
#define OFF_HB    ((size_t)0)            // 51,200,000
#define OFF_HL    ((size_t)51200000)     // 1,600,000
#define OFF_HR    ((size_t)52800000)     // 1,600,000
#define OFF_CNT   ((size_t)54400000)     // 400,128
#define OFF_OFFS  ((size_t)54800128)     // 400,128
#define OFF_CUR   ((size_t)55200256)     // 400,128
#define OFF_CSORT ((size_t)55600384)     // 6,400,000
#define OFF_ESORT ((size_t)62000384)     // E * 8 = 12,800,000 (bf16 x4)
#define OFF_BSUM  ((size_t)74800384)     // 4,096
#define OFF_WP    ((size_t)74804480)     // 131,072 (fragment-packed W)

__device__ inline float bf2f(ushort u) { return __uint_as_float((uint)u << 16); }
__device__ inline ushort f2bf(float f) {
  __hip_bfloat16 b = __float2bfloat16(f);
  return *(ushort*)&b;
}

// ---------------- prep: W fragment-pack (blocks 0-15) + hist (blocks 16+) ----------------
#define PREP_CAST_BLKS 16
#define PREP_HIST_BLKS 512

__global__ __launch_bounds__(256) void prep_kernel(const float* __restrict__ W,
                                                   ushort* __restrict__ Wp,
                                                   const int* __restrict__ row,
                                                   int* __restrict__ counts, int E) {
  if (blockIdx.x < PREP_CAST_BLKS) {
    #pragma unroll
    for (int it = 0; it < 2; ++it) {
      const int f = blockIdx.x * 512 + it * 256 + threadIdx.x;
      const int lane = f & 63;
      const int j = (f >> 6) & 3;
      const int k = (f >> 8) & 7;
      const int h = f >> 11;
      const int lr = lane & 15;
      const int kq = lane >> 4;
      const int colW = h * 64 + j * 16 + lr;
      union { ushort u[8]; short8 s; } t;
      #pragma unroll
      for (int e = 0; e < 8; ++e)
        t.u[e] = f2bf(W[(size_t)(k * 32 + kq * 8 + e) * F_TOT + colW]);
      *(short8*)&Wp[(size_t)f * 8] = t.s;
    }
  } else {
    int gtid = (blockIdx.x - PREP_CAST_BLKS) * 256 + threadIdx.x;
    for (int i = gtid; i < E; i += PREP_HIST_BLKS * 256)
      atomicAdd(&counts[row[i]], 1);
  }
}

// ---------------- MFMA GEMM (R17): one barrier pre-MFMA, packed B, LDS-transposed store ----------------
#define GBM 64
#define NRBLK 1563   // ceil(100000/64)

__global__ __launch_bounds__(256) void gemm_bf16(const float* __restrict__ X,
                                                 const ushort* __restrict__ Wp,
                                                 ushort* __restrict__ hb,
                                                 const float* __restrict__ a_l,
                                                 const float* __restrict__ a_r,
                                                 float* __restrict__ hl,
                                                 float* __restrict__ hr, int M) {
  __shared__ __align__(16) ushort Xs[GBM][IN_FEATS + 8];   // 33,792 B
  const int row0 = blockIdx.x * GBM;
  const int tid = threadIdx.x;
  const int lane = tid & 63;
  const int head = tid >> 6;
  const int lr = lane & 15;
  const int kq = lane >> 4;

  #pragma unroll
  for (int it = 0; it < 8; ++it) {
    const int ch = it * 256 + tid;
    const int r = ch >> 5;
    const int c8 = (ch & 31) * 8;
    const int gr = row0 + r;
    union { ushort u[8]; short8 s; } t;
    if (gr < M) {
      const float* src = &X[(size_t)gr * IN_FEATS + c8];
      const float4 f0 = *(const float4*)(src);
      const float4 f1 = *(const float4*)(src + 4);
      t.u[0] = f2bf(f0.x); t.u[1] = f2bf(f0.y); t.u[2] = f2bf(f0.z); t.u[3] = f2bf(f0.w);
      t.u[4] = f2bf(f1.x); t.u[5] = f2bf(f1.y); t.u[6] = f2bf(f1.z); t.u[7] = f2bf(f1.w);
    } else {
      t.s = (short8)(0);
    }
    *(short8*)&Xs[r][c8] = t.s;
  }
  __syncthreads();   // barrier 1: staging ready

  f32x4 acc[4][4];
  #pragma unroll
  for (int i = 0; i < 4; ++i)
    #pragma unroll
    for (int j = 0; j < 4; ++j) acc[i][j] = (f32x4)(0.f);

  const ushort* wpBase = &Wp[(size_t)(head * 8) * 4 * 64 * 8 + (size_t)lane * 8];

  #pragma unroll
  for (int k = 0; k < 8; ++k) {
    short8 af[4], bf[4];
    #pragma unroll
    for (int i = 0; i < 4; ++i)
      af[i] = *(const short8*)&Xs[i * 16 + lr][k * 32 + kq * 8];
    #pragma unroll
    for (int j = 0; j < 4; ++j)
      bf[j] = *(const short8*)&wpBase[(size_t)(k * 4 + j) * 64 * 8];
    #pragma unroll
    for (int i = 0; i < 4; ++i)
      #pragma unroll
      for (int j = 0; j < 4; ++j)
        acc[i][j] = __builtin_amdgcn_mfma_f32_16x16x32_bf16(af[i], bf[j], acc[i][j], 0, 0, 0);
  }

  // epilogue A: hl/hr from regs
  {
    float alv[4], arv[4];
    #pragma unroll
    for (int j = 0; j < 4; ++j) {
      alv[j] = a_l[head * OUT_FEATS + j * 16 + lr];
      arv[j] = a_r[head * OUT_FEATS + j * 16 + lr];
    }
    #pragma unroll
    for (int i = 0; i < 4; ++i) {
      #pragma unroll
      for (int reg = 0; reg < 4; ++reg) {
        float pl = 0.f, pr = 0.f;
        #pragma unroll
        for (int j = 0; j < 4; ++j) {
          pl = fmaf(acc[i][j][reg], alv[j], pl);
          pr = fmaf(acc[i][j][reg], arv[j], pr);
        }
        #pragma unroll
        for (int d = 8; d >= 1; d >>= 1) {
          pl += __shfl_xor(pl, d);
          pr += __shfl_xor(pr, d);
        }
        if (lr == 0) {
          const int r = row0 + i * 16 + kq * 4 + reg;
          if (r < M) {
            hl[r * NHEAD + head] = pl;
            hr[r * NHEAD + head] = pr;
          }
        }
      }
    }
  }

  // epilogue B: transpose acc through Xs -> coalesced 16B stores
  __syncthreads();
  #pragma unroll
  for (int i = 0; i < 4; ++i) {
    const int rr = i * 16 + kq * 4;
    #pragma unroll
    for (int j = 0; j < 4; ++j) {
      const int cc = head * 64 + j * 16 + lr;
      #pragma unroll
      for (int reg = 0; reg < 4; ++reg)
        Xs[rr + reg][cc] = f2bf(acc[i][j][reg]);
    }
  }
  __syncthreads();
  #pragma unroll
  for (int it = 0; it < 8; ++it) {
    const int ch = it * 256 + tid;
    const int r = ch >> 5;
    const int c8 = (ch & 31) * 8;
    const int gr = row0 + r;
    if (gr < M)
      *(ush8*)&hb[(size_t)gr * F_TOT + c8] = *(const ush8*)&Xs[r][c8];
  }
}

// ---------------- CSR scan (plain launches) ----------------
__global__ __launch_bounds__(1024) void scan1_kernel(const int* __restrict__ counts,
                                                     int* __restrict__ offsets,
                                                     int* __restrict__ bsum, int n) {
  __shared__ int wsum[16];
  const int tid = threadIdx.x;
  const int lane = tid & 63;
  const int wid = tid >> 6;
  int i = blockIdx.x * 1024 + tid;
  int v = (i < n) ? counts[i] : 0;
  int inc = v;
  #pragma unroll
  for (int d = 1; d < 64; d <<= 1) {
    int t = __shfl_up(inc, d);
    if (lane >= d) inc += t;
  }
  if (lane == 63) wsum[wid] = inc;
  __syncthreads();
  if (tid < 16) {
    int x = wsum[tid];
    #pragma unroll
    for (int d = 1; d < 16; d <<= 1) {
      int t = __shfl_up(x, d);
      if (tid >= d) x += t;
    }
    wsum[tid] = x;
  }
  __syncthreads();
  int excl = ((wid > 0) ? wsum[wid - 1] : 0) + inc - v;
  if (i < n) offsets[i] = excl;
  if (tid == 0) bsum[blockIdx.x] = wsum[15];
}

__global__ __launch_bounds__(256) void scan3_kernel(int* __restrict__ offsets,
                                                    int* __restrict__ cursor,
                                                    const int* __restrict__ bsum,
                                                    int n, int nblk) {
  __shared__ int sb[132];
  const int tid = threadIdx.x;
  if (tid < 64) {
    int run = 0;
    for (int base = 0; base < nblk; base += 64) {
      int idx = base + tid;
      int v = (idx < nblk) ? bsum[idx] : 0;
      int inc = v;
      #pragma unroll
      for (int d = 1; d < 64; d <<= 1) {
        int t = __shfl_up(inc, d);
        if (tid >= d) inc += t;
      }
      if (idx < nblk) sb[idx] = run + inc - v;
      run += __shfl(inc, 63);
    }
    if (tid == 0) sb[nblk] = run;
  }
  __syncthreads();
  int i = blockIdx.x * blockDim.x + tid;
  if (i < n) {
    int off = offsets[i] + sb[i >> 10];
    offsets[i] = off;
    cursor[i] = off;
  }
  if (i == 0) offsets[n] = sb[nblk];
}

// ---------------- scatter + per-edge exp weights (bf16 x4 = 8B) ----------------
__global__ void scatter_esort(const int* __restrict__ row, const int* __restrict__ col,
                              const float* __restrict__ hl, const float* __restrict__ hr,
                              int* __restrict__ cursor, int* __restrict__ col_sorted,
                              ushort* __restrict__ esort, int E) {
  int i = blockIdx.x * blockDim.x + threadIdx.x;
  if (i >= E) return;
  const int r = row[i];
  const int c = col[i];
  const float4 l4 = *(const float4*)&hl[r * NHEAD];
  const float4 r4 = *(const float4*)&hr[c * NHEAD];
  float e0 = l4.x + r4.x, e1 = l4.y + r4.y, e2 = l4.z + r4.z, e3 = l4.w + r4.w;
  e0 = e0 > 0.f ? e0 : ALPHA * e0;
  e1 = e1 > 0.f ? e1 : ALPHA * e1;
  e2 = e2 > 0.f ? e2 : ALPHA * e2;
  e3 = e3 > 0.f ? e3 : ALPHA * e3;
  union { ushort u[4]; ushort4 v; } w;
  w.u[0] = f2bf(__expf(e0));
  w.u[1] = f2bf(__expf(e1));
  w.u[2] = f2bf(__expf(e2));
  w.u[3] = f2bf(__expf(e3));
  int p = atomicAdd(&cursor[r], 1);
  col_sorted[p] = c;
  *(ushort4*)&esort[(size_t)p * 4] = w.v;
}

// ---------------- aggregation: wave/node, nontemporal sequential streams ----------------
__global__ __launch_bounds__(256) void agg_kernel(const ushort* __restrict__ hb,
                                                  const int* __restrict__ col_sorted,
                                                  const ushort* __restrict__ esort,
                                                  const int* __restrict__ offsets,
                                                  float* __restrict__ out, int n) {
  int node = blockIdx.x * 4 + (threadIdx.x >> 6);
  int lane = threadIdx.x & 63;
  if (node >= n) return;
  const int s = offsets[node];
  const int t = offsets[node + 1];
  const int half = lane >> 5;
  const int fl = lane & 31;
  const int head = fl >> 3;

  float denom = 0.f;
  float a[8] = {0.f, 0.f, 0.f, 0.f, 0.f, 0.f, 0.f, 0.f};
  const size_t fo = (size_t)fl * 8;

  auto edge = [&](int ii) {
    const int c = __builtin_nontemporal_load(&col_sorted[ii]);
    const float w = bf2f(__builtin_nontemporal_load(&esort[(size_t)ii * 4 + head]));
    union { ush8 v; ushort u[8]; } hv;
    hv.v = *(const ush8*)&hb[(size_t)c * F_TOT + fo];   // cached: hb is the reused array
    denom += w;
    #pragma unroll
    for (int j = 0; j < 8; ++j) a[j] = fmaf(w, bf2f(hv.u[j]), a[j]);
  };

  int i = s + half;
  for (; i + 6 < t; i += 8) { edge(i); edge(i + 2); edge(i + 4); edge(i + 6); }
  for (; i < t; i += 2) edge(i);

  denom += __shfl_xor(denom, 32);
  #pragma unroll
  for (int j = 0; j < 8; ++j) a[j] += __shfl_xor(a[j], 32);

  const float inv = 1.f / (denom + 1e-16f);
  f32x4 o;
  o[0] = a[half * 4 + 0] * inv;
  o[1] = a[half * 4 + 1] * inv;
  o[2] = a[half * 4 + 2] * inv;
  o[3] = a[half * 4 + 3] * inv;
  __builtin_nontemporal_store(o, (f32x4*)&out[(size_t)node * F_TOT + fl * 8 + half * 4]);
}

// ---------------- launcher ----------------
extern "C" void kernel_launch(void* const* d_in, const int* in_sizes, int n_in,
                              void* d_out, int out_size, void* d_ws, size_t ws_size,
                              hipStream_t stream) {
  const float* x   = (const float*)d_in[0];
  const float* W   = (const float*)d_in[1];
  const float* a_l = (const float*)d_in[2];
  const float* a_r = (const float*)d_in[3];
  const int*   row = (const int*)d_in[4];
  const int*   col = (const int*)d_in[5];
  float* out = (float*)d_out;

  int n = in_sizes[0] / IN_FEATS;   // 100000
  int E = in_sizes[4];              // 1600000

  char* ws = (char*)d_ws;
  ushort* hb      = (ushort*)(ws + OFF_HB);
  float*  hl      = (float*)(ws + OFF_HL);
  float*  hr      = (float*)(ws + OFF_HR);
  int* counts     = (int*)(ws + OFF_CNT);
  int* offsets    = (int*)(ws + OFF_OFFS);
  int* cursor     = (int*)(ws + OFF_CUR);
  int* col_sorted = (int*)(ws + OFF_CSORT);
  ushort* esort   = (ushort*)(ws + OFF_ESORT);
  int* bsum       = (int*)(ws + OFF_BSUM);
  ushort* Wp      = (ushort*)(ws + OFF_WP);

  // 1. zero counts
  hipMemsetAsync(counts, 0, (size_t)(n + 1) * sizeof(int), stream);
  // 2. prep: W fragment-pack + histogram
  prep_kernel<<<PREP_CAST_BLKS + PREP_HIST_BLKS, 256, 0, stream>>>(W, Wp, row, counts, E);
  // 3. GEMM (R17 form)
  gemm_bf16<<<NRBLK, 256, 0, stream>>>(x, Wp, hb, a_l, a_r, hl, hr, n);
  // 4. CSR scan
  int nblk = (n + 1023) / 1024;  // 98
  scan1_kernel<<<nblk, 1024, 0, stream>>>(counts, offsets, bsum, n);
  scan3_kernel<<<(n + 255) / 256, 256, 0, stream>>>(offsets, cursor, bsum, n, nblk);
  // 5. scatter
  scatter_esort<<<(E + 255) / 256, 256, 0, stream>>>(row, col, hl, hr, cursor,
                                                     col_sorted, esort, E);
  // 6. aggregation
  agg_kernel<<<(n + 3) / 4, 256, 0, stream>>>(hb, col_sorted, esort, offsets, out, n);
}

// Round 21
// 339.269 us; speedup vs baseline: 1.3382x; 1.0187x over previous
//
#include <hip/hip_runtime.h>
#include <hip/hip_bf16.h>
#include <math.h>

#define N_NODES 100000
#define N_EDGES 1600000
#define IN_FEATS 256
#define OUT_FEATS 64
#define NHEAD 4
#define F_TOT 256
#define ALPHA 0.2f

typedef __attribute__((ext_vector_type(8))) short short8;
typedef __attribute__((ext_vector_type(8))) unsigned short ush8;
typedef __attribute__((ext_vector_type(4))) float f32x4;

// ---------------- workspace layout (bytes) ----------------
#define OFF_HB    ((size_t)0)            // 51,200,000
#define OFF_HL    ((size_t)51200000)     // 1,600,000
#define OFF_HR    ((size_t)52800000)     // 1,600,000
#define OFF_CNT   ((size_t)54400000)     // 400,128
#define OFF_OFFS  ((size_t)54800128)     // 400,128
#define OFF_CUR   ((size_t)55200256)     // 400,128
#define OFF_CSORT ((size_t)55600384)     // 6,400,000
#define OFF_ESORT ((size_t)62000384)     // E * 8 = 12,800,000 (bf16 x4)
#define OFF_BSUM  ((size_t)74800384)     // 4,096
#define OFF_WP    ((size_t)74804480)     // 131,072 (fragment-packed W)

__device__ inline float bf2f(ushort u) { return __uint_as_float((uint)u << 16); }
__device__ inline ushort f2bf(float f) {
  __hip_bfloat16 b = __float2bfloat16(f);
  return *(ushort*)&b;
}

// ---------------- prep: W fragment-pack (blocks 0-15) + hist (blocks 16+) ----------------
#define PREP_CAST_BLKS 16
#define PREP_HIST_BLKS 512

__global__ __launch_bounds__(256) void prep_kernel(const float* __restrict__ W,
                                                   ushort* __restrict__ Wp,
                                                   const int* __restrict__ row,
                                                   int* __restrict__ counts, int E) {
  if (blockIdx.x < PREP_CAST_BLKS) {
    #pragma unroll
    for (int it = 0; it < 2; ++it) {
      const int f = blockIdx.x * 512 + it * 256 + threadIdx.x;
      const int lane = f & 63;
      const int j = (f >> 6) & 3;
      const int k = (f >> 8) & 7;
      const int h = f >> 11;
      const int lr = lane & 15;
      const int kq = lane >> 4;
      const int colW = h * 64 + j * 16 + lr;
      union { ushort u[8]; short8 s; } t;
      #pragma unroll
      for (int e = 0; e < 8; ++e)
        t.u[e] = f2bf(W[(size_t)(k * 32 + kq * 8 + e) * F_TOT + colW]);
      *(short8*)&Wp[(size_t)f * 8] = t.s;
    }
  } else {
    int gtid = (blockIdx.x - PREP_CAST_BLKS) * 256 + threadIdx.x;
    for (int i = gtid; i < E; i += PREP_HIST_BLKS * 256)
      atomicAdd(&counts[row[i]], 1);
  }
}

// ---------------- MFMA GEMM (R17): one barrier pre-MFMA, packed B, LDS-transposed store ----------------
#define GBM 64
#define NRBLK 1563   // ceil(100000/64)

__global__ __launch_bounds__(256) void gemm_bf16(const float* __restrict__ X,
                                                 const ushort* __restrict__ Wp,
                                                 ushort* __restrict__ hb,
                                                 const float* __restrict__ a_l,
                                                 const float* __restrict__ a_r,
                                                 float* __restrict__ hl,
                                                 float* __restrict__ hr, int M) {
  __shared__ __align__(16) ushort Xs[GBM][IN_FEATS + 8];   // 33,792 B
  const int row0 = blockIdx.x * GBM;
  const int tid = threadIdx.x;
  const int lane = tid & 63;
  const int head = tid >> 6;
  const int lr = lane & 15;
  const int kq = lane >> 4;

  #pragma unroll
  for (int it = 0; it < 8; ++it) {
    const int ch = it * 256 + tid;
    const int r = ch >> 5;
    const int c8 = (ch & 31) * 8;
    const int gr = row0 + r;
    union { ushort u[8]; short8 s; } t;
    if (gr < M) {
      const float* src = &X[(size_t)gr * IN_FEATS + c8];
      const float4 f0 = *(const float4*)(src);
      const float4 f1 = *(const float4*)(src + 4);
      t.u[0] = f2bf(f0.x); t.u[1] = f2bf(f0.y); t.u[2] = f2bf(f0.z); t.u[3] = f2bf(f0.w);
      t.u[4] = f2bf(f1.x); t.u[5] = f2bf(f1.y); t.u[6] = f2bf(f1.z); t.u[7] = f2bf(f1.w);
    } else {
      t.s = (short8)(0);
    }
    *(short8*)&Xs[r][c8] = t.s;
  }
  __syncthreads();   // barrier 1: staging ready

  f32x4 acc[4][4];
  #pragma unroll
  for (int i = 0; i < 4; ++i)
    #pragma unroll
    for (int j = 0; j < 4; ++j) acc[i][j] = (f32x4)(0.f);

  const ushort* wpBase = &Wp[(size_t)(head * 8) * 4 * 64 * 8 + (size_t)lane * 8];

  #pragma unroll
  for (int k = 0; k < 8; ++k) {
    short8 af[4], bf[4];
    #pragma unroll
    for (int i = 0; i < 4; ++i)
      af[i] = *(const short8*)&Xs[i * 16 + lr][k * 32 + kq * 8];
    #pragma unroll
    for (int j = 0; j < 4; ++j)
      bf[j] = *(const short8*)&wpBase[(size_t)(k * 4 + j) * 64 * 8];
    #pragma unroll
    for (int i = 0; i < 4; ++i)
      #pragma unroll
      for (int j = 0; j < 4; ++j)
        acc[i][j] = __builtin_amdgcn_mfma_f32_16x16x32_bf16(af[i], bf[j], acc[i][j], 0, 0, 0);
  }

  // epilogue A: hl/hr from regs
  {
    float alv[4], arv[4];
    #pragma unroll
    for (int j = 0; j < 4; ++j) {
      alv[j] = a_l[head * OUT_FEATS + j * 16 + lr];
      arv[j] = a_r[head * OUT_FEATS + j * 16 + lr];
    }
    #pragma unroll
    for (int i = 0; i < 4; ++i) {
      #pragma unroll
      for (int reg = 0; reg < 4; ++reg) {
        float pl = 0.f, pr = 0.f;
        #pragma unroll
        for (int j = 0; j < 4; ++j) {
          pl = fmaf(acc[i][j][reg], alv[j], pl);
          pr = fmaf(acc[i][j][reg], arv[j], pr);
        }
        #pragma unroll
        for (int d = 8; d >= 1; d >>= 1) {
          pl += __shfl_xor(pl, d);
          pr += __shfl_xor(pr, d);
        }
        if (lr == 0) {
          const int r = row0 + i * 16 + kq * 4 + reg;
          if (r < M) {
            hl[r * NHEAD + head] = pl;
            hr[r * NHEAD + head] = pr;
          }
        }
      }
    }
  }

  // epilogue B: transpose acc through Xs -> coalesced 16B stores
  __syncthreads();
  #pragma unroll
  for (int i = 0; i < 4; ++i) {
    const int rr = i * 16 + kq * 4;
    #pragma unroll
    for (int j = 0; j < 4; ++j) {
      const int cc = head * 64 + j * 16 + lr;
      #pragma unroll
      for (int reg = 0; reg < 4; ++reg)
        Xs[rr + reg][cc] = f2bf(acc[i][j][reg]);
    }
  }
  __syncthreads();
  #pragma unroll
  for (int it = 0; it < 8; ++it) {
    const int ch = it * 256 + tid;
    const int r = ch >> 5;
    const int c8 = (ch & 31) * 8;
    const int gr = row0 + r;
    if (gr < M)
      *(ush8*)&hb[(size_t)gr * F_TOT + c8] = *(const ush8*)&Xs[r][c8];
  }
}

// ---------------- CSR scan (plain launches) ----------------
__global__ __launch_bounds__(1024) void scan1_kernel(const int* __restrict__ counts,
                                                     int* __restrict__ offsets,
                                                     int* __restrict__ bsum, int n) {
  __shared__ int wsum[16];
  const int tid = threadIdx.x;
  const int lane = tid & 63;
  const int wid = tid >> 6;
  int i = blockIdx.x * 1024 + tid;
  int v = (i < n) ? counts[i] : 0;
  int inc = v;
  #pragma unroll
  for (int d = 1; d < 64; d <<= 1) {
    int t = __shfl_up(inc, d);
    if (lane >= d) inc += t;
  }
  if (lane == 63) wsum[wid] = inc;
  __syncthreads();
  if (tid < 16) {
    int x = wsum[tid];
    #pragma unroll
    for (int d = 1; d < 16; d <<= 1) {
      int t = __shfl_up(x, d);
      if (tid >= d) x += t;
    }
    wsum[tid] = x;
  }
  __syncthreads();
  int excl = ((wid > 0) ? wsum[wid - 1] : 0) + inc - v;
  if (i < n) offsets[i] = excl;
  if (tid == 0) bsum[blockIdx.x] = wsum[15];
}

__global__ __launch_bounds__(256) void scan3_kernel(int* __restrict__ offsets,
                                                    int* __restrict__ cursor,
                                                    const int* __restrict__ bsum,
                                                    int n, int nblk) {
  __shared__ int sb[132];
  const int tid = threadIdx.x;
  if (tid < 64) {
    int run = 0;
    for (int base = 0; base < nblk; base += 64) {
      int idx = base + tid;
      int v = (idx < nblk) ? bsum[idx] : 0;
      int inc = v;
      #pragma unroll
      for (int d = 1; d < 64; d <<= 1) {
        int t = __shfl_up(inc, d);
        if (tid >= d) inc += t;
      }
      if (idx < nblk) sb[idx] = run + inc - v;
      run += __shfl(inc, 63);
    }
    if (tid == 0) sb[nblk] = run;
  }
  __syncthreads();
  int i = blockIdx.x * blockDim.x + tid;
  if (i < n) {
    int off = offsets[i] + sb[i >> 10];
    offsets[i] = off;
    cursor[i] = off;
  }
  if (i == 0) offsets[n] = sb[nblk];
}

// ---------------- scatter + per-edge exp weights (bf16 x4 = 8B) ----------------
__global__ void scatter_esort(const int* __restrict__ row, const int* __restrict__ col,
                              const float* __restrict__ hl, const float* __restrict__ hr,
                              int* __restrict__ cursor, int* __restrict__ col_sorted,
                              ushort* __restrict__ esort, int E) {
  int i = blockIdx.x * blockDim.x + threadIdx.x;
  if (i >= E) return;
  const int r = row[i];
  const int c = col[i];
  const float4 l4 = *(const float4*)&hl[r * NHEAD];
  const float4 r4 = *(const float4*)&hr[c * NHEAD];
  float e0 = l4.x + r4.x, e1 = l4.y + r4.y, e2 = l4.z + r4.z, e3 = l4.w + r4.w;
  e0 = e0 > 0.f ? e0 : ALPHA * e0;
  e1 = e1 > 0.f ? e1 : ALPHA * e1;
  e2 = e2 > 0.f ? e2 : ALPHA * e2;
  e3 = e3 > 0.f ? e3 : ALPHA * e3;
  union { ushort u[4]; ushort4 v; } w;
  w.u[0] = f2bf(__expf(e0));
  w.u[1] = f2bf(__expf(e1));
  w.u[2] = f2bf(__expf(e2));
  w.u[3] = f2bf(__expf(e3));
  int p = atomicAdd(&cursor[r], 1);
  col_sorted[p] = c;
  *(ushort4*)&esort[(size_t)p * 4] = w.v;
}

// ---------------- aggregation: wave/node, cached streams, nontemporal out store ----------------
__global__ __launch_bounds__(256) void agg_kernel(const ushort* __restrict__ hb,
                                                  const int* __restrict__ col_sorted,
                                                  const ushort* __restrict__ esort,
                                                  const int* __restrict__ offsets,
                                                  float* __restrict__ out, int n) {
  int node = blockIdx.x * 4 + (threadIdx.x >> 6);
  int lane = threadIdx.x & 63;
  if (node >= n) return;
  const int s = offsets[node];
  const int t = offsets[node + 1];
  const int half = lane >> 5;
  const int fl = lane & 31;
  const int head = fl >> 3;

  float denom = 0.f;
  float a[8] = {0.f, 0.f, 0.f, 0.f, 0.f, 0.f, 0.f, 0.f};
  const size_t fo = (size_t)fl * 8;

  auto edge = [&](int ii) {
    const int c = col_sorted[ii];
    const float w = bf2f(esort[(size_t)ii * 4 + head]);
    union { ush8 v; ushort u[8]; } hv;
    hv.v = *(const ush8*)&hb[(size_t)c * F_TOT + fo];
    denom += w;
    #pragma unroll
    for (int j = 0; j < 8; ++j) a[j] = fmaf(w, bf2f(hv.u[j]), a[j]);
  };

  int i = s + half;
  for (; i + 6 < t; i += 8) { edge(i); edge(i + 2); edge(i + 4); edge(i + 6); }
  for (; i < t; i += 2) edge(i);

  denom += __shfl_xor(denom, 32);
  #pragma unroll
  for (int j = 0; j < 8; ++j) a[j] += __shfl_xor(a[j], 32);

  const float inv = 1.f / (denom + 1e-16f);
  f32x4 o;
  o[0] = a[half * 4 + 0] * inv;
  o[1] = a[half * 4 + 1] * inv;
  o[2] = a[half * 4 + 2] * inv;
  o[3] = a[half * 4 + 3] * inv;
  __builtin_nontemporal_store(o, (f32x4*)&out[(size_t)node * F_TOT + fl * 8 + half * 4]);
}

// ---------------- launcher ----------------
extern "C" void kernel_launch(void* const* d_in, const int* in_sizes, int n_in,
                              void* d_out, int out_size, void* d_ws, size_t ws_size,
                              hipStream_t stream) {
  const float* x   = (const float*)d_in[0];
  const float* W   = (const float*)d_in[1];
  const float* a_l = (const float*)d_in[2];
  const float* a_r = (const float*)d_in[3];
  const int*   row = (const int*)d_in[4];
  const int*   col = (const int*)d_in[5];
  float* out = (float*)d_out;

  int n = in_sizes[0] / IN_FEATS;   // 100000
  int E = in_sizes[4];              // 1600000

  char* ws = (char*)d_ws;
  ushort* hb      = (ushort*)(ws + OFF_HB);
  float*  hl      = (float*)(ws + OFF_HL);
  float*  hr      = (float*)(ws + OFF_HR);
  int* counts     = (int*)(ws + OFF_CNT);
  int* offsets    = (int*)(ws + OFF_OFFS);
  int* cursor     = (int*)(ws + OFF_CUR);
  int* col_sorted = (int*)(ws + OFF_CSORT);
  ushort* esort   = (ushort*)(ws + OFF_ESORT);
  int* bsum       = (int*)(ws + OFF_BSUM);
  ushort* Wp      = (ushort*)(ws + OFF_WP);

  // 1. zero counts
  hipMemsetAsync(counts, 0, (size_t)(n + 1) * sizeof(int), stream);
  // 2. prep: W fragment-pack + histogram
  prep_kernel<<<PREP_CAST_BLKS + PREP_HIST_BLKS, 256, 0, stream>>>(W, Wp, row, counts, E);
  // 3. GEMM (R17 form)
  gemm_bf16<<<NRBLK, 256, 0, stream>>>(x, Wp, hb, a_l, a_r, hl, hr, n);
  // 4. CSR scan
  int nblk = (n + 1023) / 1024;  // 98
  scan1_kernel<<<nblk, 1024, 0, stream>>>(counts, offsets, bsum, n);
  scan3_kernel<<<(n + 255) / 256, 256, 0, stream>>>(offsets, cursor, bsum, n, nblk);
  // 5. scatter
  scatter_esort<<<(E + 255) / 256, 256, 0, stream>>>(row, col, hl, hr, cursor,
                                                     col_sorted, esort, E);
  // 6. aggregation
  agg_kernel<<<(n + 3) / 4, 256, 0, stream>>>(hb, col_sorted, esort, offsets, out, n);
}